// Round 2
// baseline (224.352 us; speedup 1.0000x reference)
//
#include <hip/hip_runtime.h>

// YOLOv1 loss: batch x 7 x 7 x 30 fp32 inputs (y_trues, y_preds) -> scalar.
// R1 lesson: per-thread 120B-strided loads are TA/address-divergence-bound
// (64 lines touched per load instr). Fix: fully-coalesced float4 staging
// through LDS, two-phase (yt then yp) in one 30KB buffer -> 5 blocks/CU.

#define SS 49                       // S*S
#define DD 30                       // C + 5*B
#define CPB 256                     // cells per block == threads per block
#define F4B (CPB * DD / 4)          // 1920 float4 per tensor per block

__global__ __launch_bounds__(256)
void yolo_loss_kernel(const float4* __restrict__ yt4,
                      const float4* __restrict__ yp4,
                      float* __restrict__ out,
                      int nf4_total, int ncells, float inv_batch) {
    const float LAMBDA_COORD = 5.0f;
    const float LAMBDA_NOOBJ = 0.5f;
    const float EPS = 1e-6f;

    __shared__ float4 sbuf4[F4B];   // 30720 B
    float* sbuf = reinterpret_cast<float*>(sbuf4);

    const int tid = threadIdx.x;
    const int f4base = blockIdx.x * F4B;
    const int cell = blockIdx.x * CPB + tid;
    const bool valid = cell < ncells;

    // ---- phase 1: stage y_trues (coalesced float4), pull row to registers
#pragma unroll
    for (int k = 0; k < 8; ++k) {
        int i = tid + k * 256;
        if (i < F4B && f4base + i < nf4_total) sbuf4[i] = yt4[f4base + i];
    }
    __syncthreads();

    float yt[DD];
    if (valid) {
#pragma unroll
        for (int k = 0; k < DD; ++k) yt[k] = sbuf[tid * DD + k];
    }
    __syncthreads();

    // ---- phase 2: stage y_preds into the same buffer
#pragma unroll
    for (int k = 0; k < 8; ++k) {
        int i = tid + k * 256;
        if (i < F4B && f4base + i < nf4_total) sbuf4[i] = yp4[f4base + i];
    }
    __syncthreads();

    float per_cell = 0.0f;
    if (valid) {
        const float* yp = &sbuf[tid * DD];
        float p0 = yp[0], p1 = yp[1], p2 = yp[2], p3 = yp[3], p4 = yp[4];
        float p5 = yp[5], p6 = yp[6], p7 = yp[7], p8 = yp[8], p9 = yp[9];

        float obj = (yt[4] == 1.0f) ? 1.0f : 0.0f;
        float noobj = 1.0f - obj;

        // IoU of yt box vs both pred boxes
        float tx1 = yt[0] - yt[2] * 0.5f, ty1 = yt[1] - yt[3] * 0.5f;
        float tx2 = yt[0] + yt[2] * 0.5f, ty2 = yt[1] + yt[3] * 0.5f;
        float ta = fabsf((tx2 - tx1) * (ty2 - ty1));

        float ax1 = p0 - p2 * 0.5f, ay1 = p1 - p3 * 0.5f;
        float ax2 = p0 + p2 * 0.5f, ay2 = p1 + p3 * 0.5f;
        float iw1 = fmaxf(fminf(tx2, ax2) - fmaxf(tx1, ax1), 0.0f);
        float ih1 = fmaxf(fminf(ty2, ay2) - fmaxf(ty1, ay1), 0.0f);
        float inter1 = iw1 * ih1;
        float aa = fabsf((ax2 - ax1) * (ay2 - ay1));
        float iou1 = inter1 / (ta + aa - inter1 + EPS);

        float bx1 = p5 - p7 * 0.5f, by1 = p6 - p8 * 0.5f;
        float bx2 = p5 + p7 * 0.5f, by2 = p6 + p8 * 0.5f;
        float iw2 = fmaxf(fminf(tx2, bx2) - fmaxf(tx1, bx1), 0.0f);
        float ih2 = fmaxf(fminf(ty2, by2) - fmaxf(ty1, by1), 0.0f);
        float inter2 = iw2 * ih2;
        float ba = fabsf((bx2 - bx1) * (by2 - by1));
        float iou2 = inter2 / (ta + ba - inter2 + EPS);

        bool best1 = iou1 > iou2;
        float bh0 = best1 ? p0 : p5;
        float bh1 = best1 ? p1 : p6;
        float bh2 = best1 ? p2 : p7;
        float bh3 = best1 ? p3 : p8;
        float conf_hat       = best1 ? p4 : p9;
        float other_conf_hat = best1 ? p9 : p4;

        float dx = yt[0] - bh0, dy = yt[1] - bh1;
        float xy = dx * dx + dy * dy;

        float sw = sqrtf(yt[2]) - sqrtf(fabsf(bh2 + EPS));
        float sh = sqrtf(yt[3]) - sqrtf(fabsf(bh3 + EPS));
        float wh = sw * sw + sh * sh;

        float dc = yt[4] - conf_hat;
        float obj_conf = dc * dc;

        float noobj_in_obj = LAMBDA_NOOBJ * other_conf_hat * other_conf_hat;

        float d4 = yt[4] - p4;
        float d9 = yt[4] - p9;
        float noobj_cells = LAMBDA_NOOBJ * (d4 * d4 + d9 * d9);

        float cls = 0.0f;
#pragma unroll
        for (int k = 10; k < DD; ++k) {
            float d = yt[k] - yp[k];
            cls += d * d;
        }

        per_cell = obj * (LAMBDA_COORD * (xy + wh) + obj_conf + noobj_in_obj + cls)
                 + noobj * noobj_cells;
    }

    // Wave reduce (64 lanes) -> cross-wave LDS -> one atomic per block.
#pragma unroll
    for (int off = 32; off > 0; off >>= 1)
        per_cell += __shfl_down(per_cell, off, 64);

    __shared__ float wsum[4];
    int lane = tid & 63;
    int wave = tid >> 6;
    if (lane == 0) wsum[wave] = per_cell;
    __syncthreads();
    if (tid == 0) {
        float s = wsum[0] + wsum[1] + wsum[2] + wsum[3];
        atomicAdd(out, s * inv_batch);
    }
}

extern "C" void kernel_launch(void* const* d_in, const int* in_sizes, int n_in,
                              void* d_out, int out_size, void* d_ws, size_t ws_size,
                              hipStream_t stream) {
    const float4* yt4 = (const float4*)d_in[0];
    const float4* yp4 = (const float4*)d_in[1];
    float* out = (float*)d_out;

    int total = in_sizes[0];              // batch * 49 * 30 floats
    int ncells = total / DD;
    int batch = ncells / SS;
    int nf4 = total / 4;

    hipMemsetAsync(out, 0, sizeof(float), stream);

    int grid = (ncells + CPB - 1) / CPB;
    yolo_loss_kernel<<<grid, CPB, 0, stream>>>(yt4, yp4, out, nf4, ncells,
                                               1.0f / (float)batch);
}

// Round 3
// 213.670 us; speedup vs baseline: 1.0500x; 1.0500x over previous
//
#include <hip/hip_runtime.h>

// YOLOv1 loss: batch x 7 x 7 x 30 fp32 (y_trues, y_preds) -> scalar.
// R1: 1 thread/cell, dwordx2 direct loads -> 77 us (TA/issue-bound theory).
// R2: LDS-transpose staging -> 96 us REGRESSION (barriers + 60 LDS ops/cell
//     cost more than coalescing won; data touched once, LDS buys nothing).
// R3: 2 cells/thread -> each thread owns a 240B 16B-aligned chunk, loads it
//     as 15+15 global_load_dwordx4. Halves per-byte vmem instruction count
//     vs R1, doubles per-thread MLP, no LDS, no barriers.

#define SS 49
#define DD 30

__device__ __forceinline__ float cell_loss(const float* __restrict__ yt,
                                           const float* __restrict__ yp) {
    const float LAMBDA_COORD = 5.0f;
    const float LAMBDA_NOOBJ = 0.5f;
    const float EPS = 1e-6f;

    float obj = (yt[4] == 1.0f) ? 1.0f : 0.0f;
    float noobj = 1.0f - obj;

    float tx1 = yt[0] - yt[2] * 0.5f, ty1 = yt[1] - yt[3] * 0.5f;
    float tx2 = yt[0] + yt[2] * 0.5f, ty2 = yt[1] + yt[3] * 0.5f;
    float ta = fabsf((tx2 - tx1) * (ty2 - ty1));

    float ax1 = yp[0] - yp[2] * 0.5f, ay1 = yp[1] - yp[3] * 0.5f;
    float ax2 = yp[0] + yp[2] * 0.5f, ay2 = yp[1] + yp[3] * 0.5f;
    float iw1 = fmaxf(fminf(tx2, ax2) - fmaxf(tx1, ax1), 0.0f);
    float ih1 = fmaxf(fminf(ty2, ay2) - fmaxf(ty1, ay1), 0.0f);
    float inter1 = iw1 * ih1;
    float aa = fabsf((ax2 - ax1) * (ay2 - ay1));
    float iou1 = inter1 / (ta + aa - inter1 + EPS);

    float bx1 = yp[5] - yp[7] * 0.5f, by1 = yp[6] - yp[8] * 0.5f;
    float bx2 = yp[5] + yp[7] * 0.5f, by2 = yp[6] + yp[8] * 0.5f;
    float iw2 = fmaxf(fminf(tx2, bx2) - fmaxf(tx1, bx1), 0.0f);
    float ih2 = fmaxf(fminf(ty2, by2) - fmaxf(ty1, by1), 0.0f);
    float inter2 = iw2 * ih2;
    float ba = fabsf((bx2 - bx1) * (by2 - by1));
    float iou2 = inter2 / (ta + ba - inter2 + EPS);

    bool best1 = iou1 > iou2;
    float bh0 = best1 ? yp[0] : yp[5];
    float bh1 = best1 ? yp[1] : yp[6];
    float bh2 = best1 ? yp[2] : yp[7];
    float bh3 = best1 ? yp[3] : yp[8];
    float conf_hat       = best1 ? yp[4] : yp[9];
    float other_conf_hat = best1 ? yp[9] : yp[4];

    float dx = yt[0] - bh0, dy = yt[1] - bh1;
    float xy = dx * dx + dy * dy;

    float sw = sqrtf(yt[2]) - sqrtf(fabsf(bh2 + EPS));
    float sh = sqrtf(yt[3]) - sqrtf(fabsf(bh3 + EPS));
    float wh = sw * sw + sh * sh;

    float dc = yt[4] - conf_hat;
    float obj_conf = dc * dc;

    float noobj_in_obj = LAMBDA_NOOBJ * other_conf_hat * other_conf_hat;

    float d4 = yt[4] - yp[4];
    float d9 = yt[4] - yp[9];
    float noobj_cells = LAMBDA_NOOBJ * (d4 * d4 + d9 * d9);

    float cls = 0.0f;
#pragma unroll
    for (int k = 10; k < DD; ++k) {
        float d = yt[k] - yp[k];
        cls += d * d;
    }

    return obj * (LAMBDA_COORD * (xy + wh) + obj_conf + noobj_in_obj + cls)
         + noobj * noobj_cells;
}

__global__ __launch_bounds__(256)
void yolo_loss_kernel(const float4* __restrict__ yt4,
                      const float4* __restrict__ yp4,
                      float* __restrict__ out,
                      int npairs, float inv_batch) {
    int pair = blockIdx.x * blockDim.x + threadIdx.x;
    float acc = 0.0f;

    if (pair < npairs) {
        // 2 cells = 60 floats = 15 float4, 16B-aligned (240B chunk).
        const float4* tb = yt4 + (size_t)pair * 15;
        const float4* pb = yp4 + (size_t)pair * 15;
        float t[60], p[60];
#pragma unroll
        for (int i = 0; i < 15; ++i) {
            float4 v = tb[i];
            t[4 * i + 0] = v.x; t[4 * i + 1] = v.y;
            t[4 * i + 2] = v.z; t[4 * i + 3] = v.w;
        }
#pragma unroll
        for (int i = 0; i < 15; ++i) {
            float4 v = pb[i];
            p[4 * i + 0] = v.x; p[4 * i + 1] = v.y;
            p[4 * i + 2] = v.z; p[4 * i + 3] = v.w;
        }
        acc = cell_loss(t, p) + cell_loss(t + DD, p + DD);
    }

    // Wave reduce (64 lanes) -> cross-wave LDS -> one atomic per block.
#pragma unroll
    for (int off = 32; off > 0; off >>= 1)
        acc += __shfl_down(acc, off, 64);

    __shared__ float wsum[4];
    int lane = threadIdx.x & 63;
    int wave = threadIdx.x >> 6;
    if (lane == 0) wsum[wave] = acc;
    __syncthreads();
    if (threadIdx.x == 0) {
        float s = wsum[0] + wsum[1] + wsum[2] + wsum[3];
        atomicAdd(out, s * inv_batch);
    }
}

extern "C" void kernel_launch(void* const* d_in, const int* in_sizes, int n_in,
                              void* d_out, int out_size, void* d_ws, size_t ws_size,
                              hipStream_t stream) {
    const float4* yt4 = (const float4*)d_in[0];
    const float4* yp4 = (const float4*)d_in[1];
    float* out = (float*)d_out;

    int total = in_sizes[0];          // batch * 49 * 30 floats
    int ncells = total / DD;
    int batch = ncells / SS;
    int npairs = ncells / 2;          // 802816 cells -> 401408 pairs

    hipMemsetAsync(out, 0, sizeof(float), stream);

    int block = 256;
    int grid = (npairs + block - 1) / block;   // 1568 blocks exactly
    yolo_loss_kernel<<<grid, block, 0, stream>>>(yt4, yp4, out, npairs,
                                                 1.0f / (float)batch);
}